// Round 2
// baseline (186.514 us; speedup 1.0000x reference)
//
#include <hip/hip_runtime.h>

#define D    512
#define NB1  256
#define NB2  512

typedef unsigned int   uint_t;
typedef unsigned short ushort_t;

struct alignas(16) F4 { float  c[4]; };
struct alignas(16) U4 { uint_t c[4]; };

__device__ __forceinline__ F4 ld4(const float* p)   { return *(const F4*)p; }
__device__ __forceinline__ U4 ldu4(const uint_t* p) { return *(const U4*)p; }

__device__ __forceinline__ ushort_t f2bf(float f) {
    uint_t u = __float_as_uint(f);
    u += 0x7fffu + ((u >> 16) & 1u);   // RNE
    return (ushort_t)(u >> 16);
}

// ---------------- normalize rows -> f32
__global__ __launch_bounds__(256) void norm_f32_kernel(const float* __restrict__ src,
                                                       float* __restrict__ dst) {
    int gw = (blockIdx.x * blockDim.x + threadIdx.x) >> 6;
    int lane = threadIdx.x & 63;
    const float* r = src + (size_t)gw * D;
    float v[8];
    float s = 0.f;
#pragma unroll
    for (int i = 0; i < 8; ++i) { v[i] = r[i * 64 + lane]; s += v[i] * v[i]; }
#pragma unroll
    for (int off = 32; off; off >>= 1) s += __shfl_xor(s, off);
    float inv = 1.f / fmaxf(sqrtf(s), 1e-12f);
    float* w = dst + (size_t)gw * D;
#pragma unroll
    for (int i = 0; i < 8; ++i) w[i * 64 + lane] = v[i] * inv;
}

// ---------------- normalize rows -> bf16
__global__ __launch_bounds__(256) void norm_bf16_kernel(const float* __restrict__ src,
                                                        ushort_t* __restrict__ dst) {
    int gw = (blockIdx.x * blockDim.x + threadIdx.x) >> 6;
    int lane = threadIdx.x & 63;
    const float* r = src + (size_t)gw * D;
    float v[8];
    float s = 0.f;
#pragma unroll
    for (int i = 0; i < 8; ++i) { v[i] = r[i * 64 + lane]; s += v[i] * v[i]; }
#pragma unroll
    for (int off = 32; off; off >>= 1) s += __shfl_xor(s, off);
    float inv = 1.f / fmaxf(sqrtf(s), 1e-12f);
    ushort_t* w = dst + (size_t)gw * D;
#pragma unroll
    for (int i = 0; i < 8; ++i) w[i * 64 + lane] = f2bf(v[i] * inv);
}

// ---------------- cert2 (layers 1,2) -> bf16
__global__ __launch_bounds__(256) void cvt_bf16_kernel(const float* __restrict__ src,
                                                       ushort_t* __restrict__ dst) {
    int t = blockIdx.x * blockDim.x + threadIdx.x;
    F4 v = ld4(src + (size_t)t * 4);
    uint2 o;
    o.x = (uint_t)f2bf(v.c[0]) | ((uint_t)f2bf(v.c[1]) << 16);
    o.y = (uint_t)f2bf(v.c[2]) | ((uint_t)f2bf(v.c[3]) << 16);
    *(uint2*)(dst + (size_t)t * 4) = o;
}

// ---------------- top-3 per column, swizzle-packed indices + normalized weights
__global__ __launch_bounds__(64) void topk_kernel(const float* __restrict__ links,
                                                  uint_t* __restrict__ pidx,
                                                  float* __restrict__ wval) {
    int gw = blockIdx.x;          // l*512 + e
    int lane = threadIdx.x;
    int l = gw >> 9;
    int e = gw & (D - 1);
    const float* base = links + (size_t)l * D * D + e;
    float v[8];
#pragma unroll
    for (int i = 0; i < 8; ++i) v[i] = base[(size_t)(i * 64 + lane) * D];
    float mv[3];
    int mi[3];
    for (int k = 0; k < 3; ++k) {
        float lm = -1.f;
        int li = 0x7fffffff;
#pragma unroll
        for (int i = 0; i < 8; ++i)
            if (v[i] > lm) { lm = v[i]; li = i * 64 + lane; }
#pragma unroll
        for (int off = 32; off; off >>= 1) {
            float ov = __shfl_xor(lm, off);
            int oi = __shfl_xor(li, off);
            if (ov > lm || (ov == lm && oi < li)) { lm = ov; li = oi; }
        }
        mv[k] = lm;
        mi[k] = li;
        if (li < D && (li & 63) == lane) v[li >> 6] = -1.f;
    }
    if (lane == 0) {
        float invs = 1.f / (mv[0] + mv[1] + mv[2] + 1e-8f);
        uint_t f0 = (uint_t)mi[0] ^ (((uint_t)mi[0] >> 3) & 7u);
        uint_t f1 = (uint_t)mi[1] ^ (((uint_t)mi[1] >> 3) & 7u);
        uint_t f2 = (uint_t)mi[2] ^ (((uint_t)mi[2] >> 3) & 7u);
        pidx[gw] = f0 | (f1 << 9) | (f2 << 18);
        wval[(l * 3 + 0) * D + e] = mv[0] * invs;
        wval[(l * 3 + 1) * D + e] = mv[1] * invs;
        wval[(l * 3 + 2) * D + e] = mv[2] * invs;
    }
}

// ---------------- fused main kernel: one wave per b, 32 n's in 8 groups of 4
__global__ __launch_bounds__(128) void avsl_main_kernel(
    const float* __restrict__ n1,      // (3,B1,D) f32 normalized emb1
    const ushort_t* __restrict__ n2h,  // (3,B2,D) bf16 normalized emb2
    const float* __restrict__ cert1,   // (3,B1,D) f32
    const ushort_t* __restrict__ c2h,  // (2,B2,D) bf16 cert2 layers 1,2
    const uint_t* __restrict__ pidx,   // (2,D) phi-swizzled packed top-3 indices
    const float* __restrict__ wval,    // (2,3,D) normalized weights
    const float* __restrict__ alpha,   // (2,D)
    const float* __restrict__ beta,    // (2,D)
    float* __restrict__ out)           // (B1,B2)
{
    __shared__ F4 vbuf[2][2][D];   // [wave][v0/v1][phi(e)] -> 4 n-values
    const int lane = threadIdx.x & 63;
    const int wid  = threadIdx.x >> 6;
    const int gw = blockIdx.x * 2 + wid;    // 0..4095
    const int b  = gw >> 4;                 // 0..255
    const int n0 = (gw & 15) * 32;

    F4* vb0 = &vbuf[wid][0][0];
    F4* vb1 = &vbuf[wid][1][0];

    // persistent per-b tables; slot (i,j): e = i*256 + 4*lane + j
    F4 a0[2], a1[2], a2[2], acn1[2], acn2[2], btn1[2], btn2[2];
    F4 w1[3][2], w2[3][2];
    U4 pid1[2], pid2[2];
    int wslot[2][4];

#pragma unroll
    for (int i = 0; i < 2; ++i) {
        const int e0 = i * 256 + (lane << 2);
        a0[i] = ld4(n1 + (size_t)(0 * NB1 + b) * D + e0);
        a1[i] = ld4(n1 + (size_t)(1 * NB1 + b) * D + e0);
        a2[i] = ld4(n1 + (size_t)(2 * NB1 + b) * D + e0);
        F4 al1 = ld4(alpha + e0);
        F4 al2 = ld4(alpha + D + e0);
        F4 c11 = ld4(cert1 + (size_t)(1 * NB1 + b) * D + e0);
        F4 c12 = ld4(cert1 + (size_t)(2 * NB1 + b) * D + e0);
        F4 b1 = ld4(beta + e0);
        F4 b2 = ld4(beta + D + e0);
#pragma unroll
        for (int j = 0; j < 4; ++j) {
            acn1[i].c[j] = -al1.c[j] * c11.c[j];
            acn2[i].c[j] = -al2.c[j] * c12.c[j];
            btn1[i].c[j] = -b1.c[j];
            btn2[i].c[j] = -b2.c[j];
            int e = e0 + j;
            wslot[i][j] = e ^ ((e >> 3) & 7);
        }
#pragma unroll
        for (int k = 0; k < 3; ++k) {
            w1[k][i] = ld4(wval + k * D + e0);
            w2[k][i] = ld4(wval + (3 + k) * D + e0);
        }
        pid1[i] = ldu4(pidx + e0);
        pid2[i] = ldu4(pidx + D + e0);
    }

#pragma unroll 1
    for (int g = 0; g < 8; ++g) {
        const int n = n0 + g * 4;

        // ---------- layer 0: v0 = (a0 - r0)^2
        F4 v0s[2][4];
#pragma unroll
        for (int nn = 0; nn < 4; ++nn)
#pragma unroll
            for (int i = 0; i < 2; ++i) {
                uint2 u = *(const uint2*)(n2h + (size_t)(0 * NB2 + n + nn) * D + i * 256 + (lane << 2));
                float f0 = __uint_as_float(u.x << 16);
                float f1 = __uint_as_float(u.x & 0xffff0000u);
                float f2 = __uint_as_float(u.y << 16);
                float f3 = __uint_as_float(u.y & 0xffff0000u);
                float d;
                d = a0[i].c[0] - f0; v0s[i][0].c[nn] = d * d;
                d = a0[i].c[1] - f1; v0s[i][1].c[nn] = d * d;
                d = a0[i].c[2] - f2; v0s[i][2].c[nn] = d * d;
                d = a0[i].c[3] - f3; v0s[i][3].c[nn] = d * d;
            }
#pragma unroll
        for (int i = 0; i < 2; ++i)
#pragma unroll
            for (int j = 0; j < 4; ++j)
                vb0[wslot[i][j]] = v0s[i][j];

        // ---------- layer 1: v1 = g + P*(node - g)
        F4 r1[4][2], cc[4][2];
#pragma unroll
        for (int nn = 0; nn < 4; ++nn)
#pragma unroll
            for (int i = 0; i < 2; ++i) {
                uint2 u = *(const uint2*)(n2h + (size_t)(1 * NB2 + n + nn) * D + i * 256 + (lane << 2));
                r1[nn][i].c[0] = __uint_as_float(u.x << 16);
                r1[nn][i].c[1] = __uint_as_float(u.x & 0xffff0000u);
                r1[nn][i].c[2] = __uint_as_float(u.y << 16);
                r1[nn][i].c[3] = __uint_as_float(u.y & 0xffff0000u);
                uint2 w = *(const uint2*)(c2h + (size_t)(0 * NB2 + n + nn) * D + i * 256 + (lane << 2));
                cc[nn][i].c[0] = __uint_as_float(w.x << 16);
                cc[nn][i].c[1] = __uint_as_float(w.x & 0xffff0000u);
                cc[nn][i].c[2] = __uint_as_float(w.y << 16);
                cc[nn][i].c[3] = __uint_as_float(w.y & 0xffff0000u);
            }
#pragma unroll
        for (int i = 0; i < 2; ++i)
#pragma unroll
            for (int j = 0; j < 4; ++j) {
                uint_t p = pid1[i].c[j];
                F4 ga = vb0[p & 511];
                F4 gb = vb0[(p >> 9) & 511];
                F4 gc = vb0[(p >> 18) & 511];
                float wA = w1[0][i].c[j], wB = w1[1][i].c[j], wC = w1[2][i].c[j];
                float ac = acn1[i].c[j], bt = btn1[i].c[j], av = a1[i].c[j];
                F4 ov;
#pragma unroll
                for (int nn = 0; nn < 4; ++nn) {
                    float gs = wA * ga.c[nn] + wB * gb.c[nn] + wC * gc.c[nn];
                    float t = ac * cc[nn][i].c[j] + bt;
                    float P = __builtin_amdgcn_rcpf(1.f + __expf(t));
                    float d = av - r1[nn][i].c[j];
                    ov.c[nn] = gs + P * (d * d - gs);
                }
                vb1[wslot[i][j]] = ov;
            }

        // ---------- layer 2: acc += g + P*(node - g)
        F4 r2[4][2], cc2[4][2];
#pragma unroll
        for (int nn = 0; nn < 4; ++nn)
#pragma unroll
            for (int i = 0; i < 2; ++i) {
                uint2 u = *(const uint2*)(n2h + (size_t)(2 * NB2 + n + nn) * D + i * 256 + (lane << 2));
                r2[nn][i].c[0] = __uint_as_float(u.x << 16);
                r2[nn][i].c[1] = __uint_as_float(u.x & 0xffff0000u);
                r2[nn][i].c[2] = __uint_as_float(u.y << 16);
                r2[nn][i].c[3] = __uint_as_float(u.y & 0xffff0000u);
                uint2 w = *(const uint2*)(c2h + (size_t)(1 * NB2 + n + nn) * D + i * 256 + (lane << 2));
                cc2[nn][i].c[0] = __uint_as_float(w.x << 16);
                cc2[nn][i].c[1] = __uint_as_float(w.x & 0xffff0000u);
                cc2[nn][i].c[2] = __uint_as_float(w.y << 16);
                cc2[nn][i].c[3] = __uint_as_float(w.y & 0xffff0000u);
            }
        F4 acc;
        acc.c[0] = acc.c[1] = acc.c[2] = acc.c[3] = 0.f;
#pragma unroll
        for (int i = 0; i < 2; ++i)
#pragma unroll
            for (int j = 0; j < 4; ++j) {
                uint_t p = pid2[i].c[j];
                F4 ga = vb1[p & 511];
                F4 gb = vb1[(p >> 9) & 511];
                F4 gc = vb1[(p >> 18) & 511];
                float wA = w2[0][i].c[j], wB = w2[1][i].c[j], wC = w2[2][i].c[j];
                float ac = acn2[i].c[j], bt = btn2[i].c[j], av = a2[i].c[j];
#pragma unroll
                for (int nn = 0; nn < 4; ++nn) {
                    float gs = wA * ga.c[nn] + wB * gb.c[nn] + wC * gc.c[nn];
                    float t = ac * cc2[nn][i].c[j] + bt;
                    float P = __builtin_amdgcn_rcpf(1.f + __expf(t));
                    float d = av - r2[nn][i].c[j];
                    acc.c[nn] += gs + P * (d * d - gs);
                }
            }

        // ---------- reduce over lanes, store 4 outputs
#pragma unroll
        for (int nn = 0; nn < 4; ++nn) {
            float s = acc.c[nn];
            s += __shfl_xor(s, 32);
            s += __shfl_xor(s, 16);
            s += __shfl_xor(s, 8);
            s += __shfl_xor(s, 4);
            s += __shfl_xor(s, 2);
            s += __shfl_xor(s, 1);
            acc.c[nn] = s;
        }
        if (lane == 0) *(F4*)(out + (size_t)b * D + n) = acc;
    }
}

extern "C" void kernel_launch(void* const* d_in, const int* in_sizes, int n_in,
                              void* d_out, int out_size, void* d_ws, size_t ws_size,
                              hipStream_t stream) {
    const float* emb1  = (const float*)d_in[0];  // (3,256,512)
    const float* cert1 = (const float*)d_in[1];  // (3,256,512)
    const float* emb2  = (const float*)d_in[2];  // (3,512,512)
    const float* cert2 = (const float*)d_in[3];  // (3,512,512)
    const float* links = (const float*)d_in[4];  // (2,512,512)
    const float* alpha = (const float*)d_in[5];  // (2,512)
    const float* beta  = (const float*)d_in[6];  // (2,512)
    float* out = (float*)d_out;                  // (256,512)

    float* n1      = (float*)d_ws;                      // 3*256*512 f32
    ushort_t* n2h  = (ushort_t*)(n1 + 3 * NB1 * D);     // 3*512*512 bf16
    ushort_t* c2h  = n2h + 3 * NB2 * D;                 // 2*512*512 bf16
    uint_t* pidx   = (uint_t*)(c2h + 2 * NB2 * D);      // 2*512 u32
    float* wval    = (float*)(pidx + 2 * D);            // 2*3*512 f32

    hipLaunchKernelGGL(norm_f32_kernel, dim3((3 * NB1) / 4), dim3(256), 0, stream, emb1, n1);
    hipLaunchKernelGGL(norm_bf16_kernel, dim3((3 * NB2) / 4), dim3(256), 0, stream, emb2, n2h);
    hipLaunchKernelGGL(cvt_bf16_kernel, dim3(512), dim3(256), 0, stream,
                       cert2 + (size_t)NB2 * D, c2h);
    hipLaunchKernelGGL(topk_kernel, dim3(2 * D), dim3(64), 0, stream, links, pidx, wval);
    hipLaunchKernelGGL(avsl_main_kernel, dim3(2048), dim3(128), 0, stream,
                       n1, n2h, cert1, c2h, pidx, wval, alpha, beta, out);
}

// Round 3
// 94.997 us; speedup vs baseline: 1.9634x; 1.9634x over previous
//
#include <hip/hip_runtime.h>

#define D    512
#define NB1  256
#define NB2  512

typedef unsigned int   uint_t;
typedef unsigned short ushort_t;

struct alignas(16) F4 { float c[4]; };

__device__ __forceinline__ F4 ld4(const float* p) { return *(const F4*)p; }
__device__ __forceinline__ float bflo(uint_t u) { return __uint_as_float(u << 16); }
__device__ __forceinline__ float bfhi(uint_t u) { return __uint_as_float(u & 0xffff0000u); }

__device__ __forceinline__ ushort_t f2bf(float f) {
    uint_t u = __float_as_uint(f);
    u += 0x7fffu + ((u >> 16) & 1u);   // RNE
    return (ushort_t)(u >> 16);
}

// ---------------- normalize rows -> f32
__global__ __launch_bounds__(256) void norm_f32_kernel(const float* __restrict__ src,
                                                       float* __restrict__ dst) {
    int gw = (blockIdx.x * blockDim.x + threadIdx.x) >> 6;
    int lane = threadIdx.x & 63;
    const float* r = src + (size_t)gw * D;
    float v[8];
    float s = 0.f;
#pragma unroll
    for (int i = 0; i < 8; ++i) { v[i] = r[i * 64 + lane]; s += v[i] * v[i]; }
#pragma unroll
    for (int off = 32; off; off >>= 1) s += __shfl_xor(s, off);
    float inv = 1.f / fmaxf(sqrtf(s), 1e-12f);
    float* w = dst + (size_t)gw * D;
#pragma unroll
    for (int i = 0; i < 8; ++i) w[i * 64 + lane] = v[i] * inv;
}

// ---------------- normalize rows -> bf16
__global__ __launch_bounds__(256) void norm_bf16_kernel(const float* __restrict__ src,
                                                        ushort_t* __restrict__ dst) {
    int gw = (blockIdx.x * blockDim.x + threadIdx.x) >> 6;
    int lane = threadIdx.x & 63;
    const float* r = src + (size_t)gw * D;
    float v[8];
    float s = 0.f;
#pragma unroll
    for (int i = 0; i < 8; ++i) { v[i] = r[i * 64 + lane]; s += v[i] * v[i]; }
#pragma unroll
    for (int off = 32; off; off >>= 1) s += __shfl_xor(s, off);
    float inv = 1.f / fmaxf(sqrtf(s), 1e-12f);
    ushort_t* w = dst + (size_t)gw * D;
#pragma unroll
    for (int i = 0; i < 8; ++i) w[i * 64 + lane] = f2bf(v[i] * inv);
}

// ---------------- cert2 (layers 1,2) -> bf16
__global__ __launch_bounds__(256) void cvt_bf16_kernel(const float* __restrict__ src,
                                                       ushort_t* __restrict__ dst) {
    int t = blockIdx.x * blockDim.x + threadIdx.x;
    F4 v = ld4(src + (size_t)t * 4);
    uint2 o;
    o.x = (uint_t)f2bf(v.c[0]) | ((uint_t)f2bf(v.c[1]) << 16);
    o.y = (uint_t)f2bf(v.c[2]) | ((uint_t)f2bf(v.c[3]) << 16);
    *(uint2*)(dst + (size_t)t * 4) = o;
}

// ---------------- top-3 per column, phi-swizzled packed indices + normalized weights
__global__ __launch_bounds__(64) void topk_kernel(const float* __restrict__ links,
                                                  uint_t* __restrict__ pidx,
                                                  float* __restrict__ wval) {
    int gw = blockIdx.x;          // l*512 + e
    int lane = threadIdx.x;
    int l = gw >> 9;
    int e = gw & (D - 1);
    const float* base = links + (size_t)l * D * D + e;
    float v[8];
#pragma unroll
    for (int i = 0; i < 8; ++i) v[i] = base[(size_t)(i * 64 + lane) * D];
    float mv[3];
    int mi[3];
    for (int k = 0; k < 3; ++k) {
        float lm = -1.f;
        int li = 0x7fffffff;
#pragma unroll
        for (int i = 0; i < 8; ++i)
            if (v[i] > lm) { lm = v[i]; li = i * 64 + lane; }
#pragma unroll
        for (int off = 32; off; off >>= 1) {
            float ov = __shfl_xor(lm, off);
            int oi = __shfl_xor(li, off);
            if (ov > lm || (ov == lm && oi < li)) { lm = ov; li = oi; }
        }
        mv[k] = lm;
        mi[k] = li;
        if (li < D && (li & 63) == lane) v[li >> 6] = -1.f;
    }
    if (lane == 0) {
        float invs = 1.f / (mv[0] + mv[1] + mv[2] + 1e-8f);
        uint_t f0 = (uint_t)mi[0] ^ (((uint_t)mi[0] >> 3) & 7u);
        uint_t f1 = (uint_t)mi[1] ^ (((uint_t)mi[1] >> 3) & 7u);
        uint_t f2 = (uint_t)mi[2] ^ (((uint_t)mi[2] >> 3) & 7u);
        pidx[gw] = f0 | (f1 << 9) | (f2 << 18);
        wval[(l * 3 + 0) * D + e] = mv[0] * invs;
        wval[(l * 3 + 1) * D + e] = mv[1] * invs;
        wval[(l * 3 + 2) * D + e] = mv[2] * invs;
    }
}

// ---------------- fused main kernel: block = (b, 32 n's); 4 waves split e; n batched by 4
__global__ __launch_bounds__(256, 4) void avsl_main_kernel(
    const float* __restrict__ n1,      // (3,B1,D) f32 normalized emb1
    const ushort_t* __restrict__ n2h,  // (3,B2,D) bf16 normalized emb2
    const float* __restrict__ cert1,   // (3,B1,D) f32
    const ushort_t* __restrict__ c2h,  // (2,B2,D) bf16 cert2 layers 1,2
    const uint_t* __restrict__ pidx,   // (2,D) phi-swizzled packed top-3 indices
    const float* __restrict__ wval,    // (2,3,D) normalized weights
    const float* __restrict__ alpha,   // (2,D)
    const float* __restrict__ beta,    // (2,D)
    float* __restrict__ out)           // (B1,B2)
{
    __shared__ F4 vbuf[2][D];          // [v0/v1][phi(e)] -> 4 n-values, block-shared
    __shared__ float pbuf[4][4];       // wave partials [wid][nn]
    const int tid  = threadIdx.x;
    const int lane = tid & 63;
    const int wid  = tid >> 6;
    const int b    = blockIdx.x >> 4;
    const int n0   = (blockIdx.x & 15) * 32;
    const int e0   = wid * 128 + lane * 2;   // this lane owns e0, e0+1

    // ---- persistent per-e tables (2 elements per lane)
    float2 a0  = *(const float2*)(n1 + (size_t)(0 * NB1 + b) * D + e0);
    float2 a1  = *(const float2*)(n1 + (size_t)(1 * NB1 + b) * D + e0);
    float2 a2  = *(const float2*)(n1 + (size_t)(2 * NB1 + b) * D + e0);
    float2 al1 = *(const float2*)(alpha + e0);
    float2 al2 = *(const float2*)(alpha + D + e0);
    float2 c11 = *(const float2*)(cert1 + (size_t)(1 * NB1 + b) * D + e0);
    float2 c12 = *(const float2*)(cert1 + (size_t)(2 * NB1 + b) * D + e0);
    float2 be1 = *(const float2*)(beta + e0);
    float2 be2 = *(const float2*)(beta + D + e0);
    const float acn1[2] = { -al1.x * c11.x, -al1.y * c11.y };
    const float acn2[2] = { -al2.x * c12.x, -al2.y * c12.y };
    const float btn1[2] = { -be1.x, -be1.y };
    const float btn2[2] = { -be2.x, -be2.y };

    float w1v[3][2], w2v[3][2];
#pragma unroll
    for (int k = 0; k < 3; ++k) {
        float2 t1 = *(const float2*)(wval + k * D + e0);
        float2 t2 = *(const float2*)(wval + (3 + k) * D + e0);
        w1v[k][0] = t1.x; w1v[k][1] = t1.y;
        w2v[k][0] = t2.x; w2v[k][1] = t2.y;
    }
    uint2 p1 = *(const uint2*)(pidx + e0);
    uint2 p2 = *(const uint2*)(pidx + D + e0);
    const int i1[3][2] = { {(int)(p1.x & 511u),         (int)(p1.y & 511u)},
                           {(int)((p1.x >> 9) & 511u),  (int)((p1.y >> 9) & 511u)},
                           {(int)((p1.x >> 18) & 511u), (int)((p1.y >> 18) & 511u)} };
    const int i2[3][2] = { {(int)(p2.x & 511u),         (int)(p2.y & 511u)},
                           {(int)((p2.x >> 9) & 511u),  (int)((p2.y >> 9) & 511u)},
                           {(int)((p2.x >> 18) & 511u), (int)((p2.y >> 18) & 511u)} };
    const int sl0 = e0 ^ ((e0 >> 3) & 7);
    const int sl1 = (e0 + 1) ^ (((e0 + 1) >> 3) & 7);

    const ushort_t* r0base = n2h + (size_t)(0 * NB2 + n0) * D + e0;
    const ushort_t* r1base = n2h + (size_t)(1 * NB2 + n0) * D + e0;
    const ushort_t* r2base = n2h + (size_t)(2 * NB2 + n0) * D + e0;
    const ushort_t* c1base = c2h + (size_t)(0 * NB2 + n0) * D + e0;
    const ushort_t* c2base = c2h + (size_t)(1 * NB2 + n0) * D + e0;

#pragma unroll 1
    for (int g = 0; g < 8; ++g) {
        const int nb = g * 4;
        uint_t r0u[4], r1u[4], r2u[4], c1u[4], c2u[4];
#pragma unroll
        for (int nn = 0; nn < 4; ++nn) {
            r0u[nn] = *(const uint_t*)(r0base + (size_t)(nb + nn) * D);
            r1u[nn] = *(const uint_t*)(r1base + (size_t)(nb + nn) * D);
            r2u[nn] = *(const uint_t*)(r2base + (size_t)(nb + nn) * D);
            c1u[nn] = *(const uint_t*)(c1base + (size_t)(nb + nn) * D);
            c2u[nn] = *(const uint_t*)(c2base + (size_t)(nb + nn) * D);
        }

        // ---------- layer 0: v0 = (a0 - r0)^2
        F4 v0a, v0b;
#pragma unroll
        for (int nn = 0; nn < 4; ++nn) {
            float d0 = a0.x - bflo(r0u[nn]);
            float d1 = a0.y - bfhi(r0u[nn]);
            v0a.c[nn] = d0 * d0;
            v0b.c[nn] = d1 * d1;
        }
        vbuf[0][sl0] = v0a;
        vbuf[0][sl1] = v0b;
        __syncthreads();

        // ---------- layer 1: v1 = g + P*(node - g)
        {
            F4 gA0 = vbuf[0][i1[0][0]], gB0 = vbuf[0][i1[1][0]], gC0 = vbuf[0][i1[2][0]];
            F4 gA1 = vbuf[0][i1[0][1]], gB1 = vbuf[0][i1[1][1]], gC1 = vbuf[0][i1[2][1]];
            F4 o0, o1;
#pragma unroll
            for (int nn = 0; nn < 4; ++nn) {
                float gs0 = w1v[0][0] * gA0.c[nn] + w1v[1][0] * gB0.c[nn] + w1v[2][0] * gC0.c[nn];
                float t0  = fmaf(acn1[0], bflo(c1u[nn]), btn1[0]);
                float P0  = __builtin_amdgcn_rcpf(1.f + __expf(t0));
                float d0  = a1.x - bflo(r1u[nn]);
                o0.c[nn]  = gs0 + P0 * (d0 * d0 - gs0);

                float gs1 = w1v[0][1] * gA1.c[nn] + w1v[1][1] * gB1.c[nn] + w1v[2][1] * gC1.c[nn];
                float t1  = fmaf(acn1[1], bfhi(c1u[nn]), btn1[1]);
                float P1  = __builtin_amdgcn_rcpf(1.f + __expf(t1));
                float d1  = a1.y - bfhi(r1u[nn]);
                o1.c[nn]  = gs1 + P1 * (d1 * d1 - gs1);
            }
            vbuf[1][sl0] = o0;
            vbuf[1][sl1] = o1;
        }
        __syncthreads();

        // ---------- layer 2: acc += g + P*(node - g)
        F4 acc;
        acc.c[0] = acc.c[1] = acc.c[2] = acc.c[3] = 0.f;
        {
            F4 gA0 = vbuf[1][i2[0][0]], gB0 = vbuf[1][i2[1][0]], gC0 = vbuf[1][i2[2][0]];
            F4 gA1 = vbuf[1][i2[0][1]], gB1 = vbuf[1][i2[1][1]], gC1 = vbuf[1][i2[2][1]];
#pragma unroll
            for (int nn = 0; nn < 4; ++nn) {
                float gs0 = w2v[0][0] * gA0.c[nn] + w2v[1][0] * gB0.c[nn] + w2v[2][0] * gC0.c[nn];
                float t0  = fmaf(acn2[0], bflo(c2u[nn]), btn2[0]);
                float P0  = __builtin_amdgcn_rcpf(1.f + __expf(t0));
                float d0  = a2.x - bflo(r2u[nn]);
                acc.c[nn] += gs0 + P0 * (d0 * d0 - gs0);

                float gs1 = w2v[0][1] * gA1.c[nn] + w2v[1][1] * gB1.c[nn] + w2v[2][1] * gC1.c[nn];
                float t1  = fmaf(acn2[1], bfhi(c2u[nn]), btn2[1]);
                float P1  = __builtin_amdgcn_rcpf(1.f + __expf(t1));
                float d1  = a2.y - bfhi(r2u[nn]);
                acc.c[nn] += gs1 + P1 * (d1 * d1 - gs1);
            }
        }

        // ---------- wave reduction: 10-shuffle split butterfly
        float pA = __shfl_xor(acc.c[0], 1);
        float pB = __shfl_xor(acc.c[1], 1);
        float pC = __shfl_xor(acc.c[2], 1);
        float pD = __shfl_xor(acc.c[3], 1);
        float u0, u1;
        if (lane & 1) { u0 = acc.c[1] + pB; u1 = acc.c[3] + pD; }
        else          { u0 = acc.c[0] + pA; u1 = acc.c[2] + pC; }
        float q0 = __shfl_xor(u0, 2);
        float q1 = __shfl_xor(u1, 2);
        float v = (lane & 2) ? (u1 + q1) : (u0 + q0);   // holds nn = lane&3
        v += __shfl_xor(v, 4);
        v += __shfl_xor(v, 8);
        v += __shfl_xor(v, 16);
        v += __shfl_xor(v, 32);
        if (lane < 4) pbuf[wid][lane] = v;
        __syncthreads();
        if (tid < 4) {
            out[(size_t)b * NB2 + n0 + nb + tid] =
                pbuf[0][tid] + pbuf[1][tid] + pbuf[2][tid] + pbuf[3][tid];
        }
    }
}

extern "C" void kernel_launch(void* const* d_in, const int* in_sizes, int n_in,
                              void* d_out, int out_size, void* d_ws, size_t ws_size,
                              hipStream_t stream) {
    const float* emb1  = (const float*)d_in[0];  // (3,256,512)
    const float* cert1 = (const float*)d_in[1];  // (3,256,512)
    const float* emb2  = (const float*)d_in[2];  // (3,512,512)
    const float* cert2 = (const float*)d_in[3];  // (3,512,512)
    const float* links = (const float*)d_in[4];  // (2,512,512)
    const float* alpha = (const float*)d_in[5];  // (2,512)
    const float* beta  = (const float*)d_in[6];  // (2,512)
    float* out = (float*)d_out;                  // (256,512)

    float* n1      = (float*)d_ws;                      // 3*256*512 f32
    ushort_t* n2h  = (ushort_t*)(n1 + 3 * NB1 * D);     // 3*512*512 bf16
    ushort_t* c2h  = n2h + 3 * NB2 * D;                 // 2*512*512 bf16
    uint_t* pidx   = (uint_t*)(c2h + 2 * NB2 * D);      // 2*512 u32
    float* wval    = (float*)(pidx + 2 * D);            // 2*3*512 f32

    hipLaunchKernelGGL(norm_f32_kernel, dim3((3 * NB1) / 4), dim3(256), 0, stream, emb1, n1);
    hipLaunchKernelGGL(norm_bf16_kernel, dim3((3 * NB2) / 4), dim3(256), 0, stream, emb2, n2h);
    hipLaunchKernelGGL(cvt_bf16_kernel, dim3(512), dim3(256), 0, stream,
                       cert2 + (size_t)NB2 * D, c2h);
    hipLaunchKernelGGL(topk_kernel, dim3(2 * D), dim3(64), 0, stream, links, pidx, wval);
    hipLaunchKernelGGL(avsl_main_kernel, dim3(4096), dim3(256), 0, stream,
                       n1, n2h, cert1, c2h, pidx, wval, alpha, beta, out);
}

// Round 4
// 85.330 us; speedup vs baseline: 2.1858x; 1.1133x over previous
//
#include <hip/hip_runtime.h>

#define D     512
#define NB1   256
#define NB2   512
#define LOG2E 1.44269504088896f

typedef unsigned int   uint_t;
typedef unsigned short ushort_t;

struct alignas(16) F4 { float c[4]; };

__device__ __forceinline__ float bflo(uint_t u) { return __uint_as_float(u << 16); }
__device__ __forceinline__ float bfhi(uint_t u) { return __uint_as_float(u & 0xffff0000u); }
__device__ __forceinline__ ushort_t f2bf(float f) {
    uint_t u = __float_as_uint(f);
    u += 0x7fffu + ((u >> 16) & 1u);   // RNE
    return (ushort_t)(u >> 16);
}

// ================= merged prep kernel =================
// blocks 0..191    : emb1 -> n1 (f32 normalized), 768 rows, 1 row/wave
// blocks 192..575  : emb2 -> n2h (bf16 normalized), 1536 rows, 1 row/wave
// blocks 576..1087 : cert2 layers 1,2 -> c2h (bf16), 4 floats/thread
// blocks 1088..1343: top-3 per column of links, 1 column/wave
__global__ __launch_bounds__(256) void prep_kernel(
    const float* __restrict__ emb1, const float* __restrict__ emb2,
    const float* __restrict__ cert2, const float* __restrict__ links,
    float* __restrict__ n1, ushort_t* __restrict__ n2h, ushort_t* __restrict__ c2h,
    uint_t* __restrict__ pidx, float* __restrict__ wval)
{
    const int blk  = blockIdx.x;
    const int lane = threadIdx.x & 63;
    const int w    = threadIdx.x >> 6;

    if (blk < 192) {                       // ---- normalize emb1 -> f32
        int row = blk * 4 + w;
        const float* r = emb1 + (size_t)row * D;
        float v[8]; float s = 0.f;
#pragma unroll
        for (int i = 0; i < 8; ++i) { v[i] = r[i * 64 + lane]; s += v[i] * v[i]; }
#pragma unroll
        for (int off = 32; off; off >>= 1) s += __shfl_xor(s, off);
        float inv = 1.f / fmaxf(sqrtf(s), 1e-12f);
        float* o = n1 + (size_t)row * D;
#pragma unroll
        for (int i = 0; i < 8; ++i) o[i * 64 + lane] = v[i] * inv;
    } else if (blk < 576) {                // ---- normalize emb2 -> bf16
        int row = (blk - 192) * 4 + w;
        const float* r = emb2 + (size_t)row * D;
        float v[8]; float s = 0.f;
#pragma unroll
        for (int i = 0; i < 8; ++i) { v[i] = r[i * 64 + lane]; s += v[i] * v[i]; }
#pragma unroll
        for (int off = 32; off; off >>= 1) s += __shfl_xor(s, off);
        float inv = 1.f / fmaxf(sqrtf(s), 1e-12f);
        ushort_t* o = n2h + (size_t)row * D;
#pragma unroll
        for (int i = 0; i < 8; ++i) o[i * 64 + lane] = f2bf(v[i] * inv);
    } else if (blk < 1088) {               // ---- cert2 layers 1,2 -> bf16
        int t = (blk - 576) * 256 + threadIdx.x;
        const float* s4 = cert2 + (size_t)NB2 * D + (size_t)t * 4;
        float4 v = *(const float4*)s4;
        uint2 o;
        o.x = (uint_t)f2bf(v.x) | ((uint_t)f2bf(v.y) << 16);
        o.y = (uint_t)f2bf(v.z) | ((uint_t)f2bf(v.w) << 16);
        *(uint2*)(c2h + (size_t)t * 4) = o;
    } else {                               // ---- top-3 per column
        int gw = (blk - 1088) * 4 + w;     // l*512 + e
        int l = gw >> 9;
        int e = gw & (D - 1);
        const float* base = links + (size_t)l * D * D + e;
        float v[8];
#pragma unroll
        for (int i = 0; i < 8; ++i) v[i] = base[(size_t)(i * 64 + lane) * D];
        float mv[3]; int mi[3];
        for (int k = 0; k < 3; ++k) {
            float lm = -1.f; int li = 0x7fffffff;
#pragma unroll
            for (int i = 0; i < 8; ++i)
                if (v[i] > lm) { lm = v[i]; li = i * 64 + lane; }
#pragma unroll
            for (int off = 32; off; off >>= 1) {
                float ov = __shfl_xor(lm, off);
                int oi = __shfl_xor(li, off);
                if (ov > lm || (ov == lm && oi < li)) { lm = ov; li = oi; }
            }
            mv[k] = lm; mi[k] = li;
            if (li < D && (li & 63) == lane) v[li >> 6] = -1.f;
        }
        if (lane == 0) {
            float invs = 1.f / (mv[0] + mv[1] + mv[2] + 1e-8f);
            uint_t f0 = (uint_t)mi[0] ^ (((uint_t)mi[0] >> 3) & 7u);
            uint_t f1 = (uint_t)mi[1] ^ (((uint_t)mi[1] >> 3) & 7u);
            uint_t f2 = (uint_t)mi[2] ^ (((uint_t)mi[2] >> 3) & 7u);
            pidx[gw] = f0 | (f1 << 9) | (f2 << 18);
            wval[(l * 3 + 0) * D + e] = mv[0] * invs;
            wval[(l * 3 + 1) * D + e] = mv[1] * invs;
            wval[(l * 3 + 2) * D + e] = mv[2] * invs;
        }
    }
}

// ================= fused main kernel =================
// block = (b, 32 n's); 4 waves split e; n batched by 4; 2-phase pipelined.
__global__ __launch_bounds__(256, 5) void avsl_main_kernel(
    const float* __restrict__ n1,      // (3,B1,D) f32 normalized emb1
    const ushort_t* __restrict__ n2h,  // (3,B2,D) bf16 normalized emb2
    const float* __restrict__ cert1,   // (3,B1,D) f32
    const ushort_t* __restrict__ c2h,  // (2,B2,D) bf16 cert2 layers 1,2
    const uint_t* __restrict__ pidx,   // (2,D) phi-swizzled packed top-3 indices
    const float* __restrict__ wval,    // (2,3,D) normalized weights
    const float* __restrict__ alpha,   // (2,D)
    const float* __restrict__ beta,    // (2,D)
    float* __restrict__ out)           // (B1,B2)
{
    __shared__ F4 vbuf[3 * D];         // [0..511]=v0 ping, [512..1023]=v0 pong, [1024..1535]=v1
    __shared__ float pbuf[16];
    const int tid  = threadIdx.x;
    const int lane = tid & 63;
    const int wid  = tid >> 6;
    const int b    = blockIdx.x >> 4;
    const int n0   = (blockIdx.x & 15) * 32;
    const int e0   = wid * 128 + lane * 2;     // lane owns e0, e0+1

    // ---- persistent per-e tables
    float2 a0  = *(const float2*)(n1 + (size_t)(0 * NB1 + b) * D + e0);
    float2 a1  = *(const float2*)(n1 + (size_t)(1 * NB1 + b) * D + e0);
    float2 a2  = *(const float2*)(n1 + (size_t)(2 * NB1 + b) * D + e0);
    float2 al1 = *(const float2*)(alpha + e0);
    float2 al2 = *(const float2*)(alpha + D + e0);
    float2 c11 = *(const float2*)(cert1 + (size_t)(1 * NB1 + b) * D + e0);
    float2 c12 = *(const float2*)(cert1 + (size_t)(2 * NB1 + b) * D + e0);
    float2 be1 = *(const float2*)(beta + e0);
    float2 be2 = *(const float2*)(beta + D + e0);
    const float acn1x = -al1.x * c11.x * LOG2E, acn1y = -al1.y * c11.y * LOG2E;
    const float acn2x = -al2.x * c12.x * LOG2E, acn2y = -al2.y * c12.y * LOG2E;
    const float btn1x = -be1.x * LOG2E, btn1y = -be1.y * LOG2E;
    const float btn2x = -be2.x * LOG2E, btn2y = -be2.y * LOG2E;

    float w1v[3][2], w2v[3][2];
#pragma unroll
    for (int k = 0; k < 3; ++k) {
        float2 t1 = *(const float2*)(wval + k * D + e0);
        float2 t2 = *(const float2*)(wval + (3 + k) * D + e0);
        w1v[k][0] = t1.x; w1v[k][1] = t1.y;
        w2v[k][0] = t2.x; w2v[k][1] = t2.y;
    }
    uint2 p1 = *(const uint2*)(pidx + e0);
    uint2 p2 = *(const uint2*)(pidx + D + e0);

    // hoisted LDS gather pointers (parity handled via [512] imm offset)
    const F4* q1a0 = &vbuf[p1.x & 511u];
    const F4* q1b0 = &vbuf[(p1.x >> 9) & 511u];
    const F4* q1c0 = &vbuf[(p1.x >> 18) & 511u];
    const F4* q1a1 = &vbuf[p1.y & 511u];
    const F4* q1b1 = &vbuf[(p1.y >> 9) & 511u];
    const F4* q1c1 = &vbuf[(p1.y >> 18) & 511u];
    const F4* q2a0 = &vbuf[1024 + (p2.x & 511u)];
    const F4* q2b0 = &vbuf[1024 + ((p2.x >> 9) & 511u)];
    const F4* q2c0 = &vbuf[1024 + ((p2.x >> 18) & 511u)];
    const F4* q2a1 = &vbuf[1024 + (p2.y & 511u)];
    const F4* q2b1 = &vbuf[1024 + ((p2.y >> 9) & 511u)];
    const F4* q2c1 = &vbuf[1024 + ((p2.y >> 18) & 511u)];
    const int sl0 = e0 ^ ((e0 >> 3) & 7);
    const int sl1 = (e0 + 1) ^ (((e0 + 1) >> 3) & 7);
    F4* qw0a = &vbuf[sl0];
    F4* qw0b = &vbuf[sl1];
    F4* qw1a = &vbuf[1024 + sl0];
    F4* qw1b = &vbuf[1024 + sl1];

    // stream pointers (advanced 4 rows per group)
    const ushort_t* pr0 = n2h + (size_t)(0 * NB2 + n0) * D + e0;
    const ushort_t* pr1 = n2h + (size_t)(1 * NB2 + n0) * D + e0;
    const ushort_t* pr2 = n2h + (size_t)(2 * NB2 + n0) * D + e0;
    const ushort_t* pc1 = c2h + (size_t)(0 * NB2 + n0) * D + e0;
    const ushort_t* pc2 = c2h + (size_t)(1 * NB2 + n0) * D + e0;

    // ---- prologue: loads for g=0, L0(0) -> v0[ping]
    uint_t r1c[4], c1c[4], r0c[4];
#pragma unroll
    for (int nn = 0; nn < 4; ++nn) {
        r0c[nn] = *(const uint_t*)(pr0 + nn * D);
        r1c[nn] = *(const uint_t*)(pr1 + nn * D);
        c1c[nn] = *(const uint_t*)(pc1 + nn * D);
    }
    {
        F4 v0a, v0b;
#pragma unroll
        for (int nn = 0; nn < 4; ++nn) {
            float d0 = a0.x - bflo(r0c[nn]);
            float d1 = a0.y - bfhi(r0c[nn]);
            v0a.c[nn] = d0 * d0;
            v0b.c[nn] = d1 * d1;
        }
        qw0a[0] = v0a;
        qw0b[0] = v0b;
    }
    __syncthreads();

#pragma unroll 2
    for (int g = 0; g < 8; ++g) {
        // ================= phase A =================
        if (g) {
            if (tid < 4)
                out[(size_t)b * NB2 + n0 + (g - 1) * 4 + tid] =
                    pbuf[tid] + pbuf[4 + tid] + pbuf[8 + tid] + pbuf[12 + tid];
        }
        // issue: r0 for g+1, r2/c2 for this g (overreads at g=7 land in next layer: in-bounds)
        uint_t r0n[4], r2c[4], c2c[4];
#pragma unroll
        for (int nn = 0; nn < 4; ++nn) {
            r0n[nn] = *(const uint_t*)(pr0 + (4 + nn) * D);
            r2c[nn] = *(const uint_t*)(pr2 + nn * D);
            c2c[nn] = *(const uint_t*)(pc2 + nn * D);
        }
        // L1: gather v0[g&1], blend, write v1
        {
            F4 gA0 = q1a0[(g & 1) * 512], gB0 = q1b0[(g & 1) * 512], gC0 = q1c0[(g & 1) * 512];
            F4 gA1 = q1a1[(g & 1) * 512], gB1 = q1b1[(g & 1) * 512], gC1 = q1c1[(g & 1) * 512];
            F4 o0, o1;
#pragma unroll
            for (int nn = 0; nn < 4; ++nn) {
                float rl = bflo(r1c[nn]), rh = bfhi(r1c[nn]);
                float cl = bflo(c1c[nn]), ch = bfhi(c1c[nn]);
                float gs0 = fmaf(w1v[0][0], gA0.c[nn], fmaf(w1v[1][0], gB0.c[nn], w1v[2][0] * gC0.c[nn]));
                float gs1 = fmaf(w1v[0][1], gA1.c[nn], fmaf(w1v[1][1], gB1.c[nn], w1v[2][1] * gC1.c[nn]));
                float P0 = __builtin_amdgcn_rcpf(1.f + __builtin_amdgcn_exp2f(fmaf(acn1x, cl, btn1x)));
                float P1 = __builtin_amdgcn_rcpf(1.f + __builtin_amdgcn_exp2f(fmaf(acn1y, ch, btn1y)));
                float d0 = a1.x - rl, d1 = a1.y - rh;
                o0.c[nn] = gs0 + P0 * (d0 * d0 - gs0);
                o1.c[nn] = gs1 + P1 * (d1 * d1 - gs1);
            }
            qw1a[0] = o0;
            qw1b[0] = o1;
        }
        __syncthreads();

        // ================= phase B =================
        // issue: r1/c1 for g+1 (overread at g=7 in-bounds)
        uint_t r1n[4], c1n[4];
#pragma unroll
        for (int nn = 0; nn < 4; ++nn) {
            r1n[nn] = *(const uint_t*)(pr1 + (4 + nn) * D);
            c1n[nn] = *(const uint_t*)(pc1 + (4 + nn) * D);
        }
        // L2: gather v1, blend, accumulate
        F4 acc;
        {
            F4 gA0 = q2a0[0], gB0 = q2b0[0], gC0 = q2c0[0];
            F4 gA1 = q2a1[0], gB1 = q2b1[0], gC1 = q2c1[0];
#pragma unroll
            for (int nn = 0; nn < 4; ++nn) {
                float rl = bflo(r2c[nn]), rh = bfhi(r2c[nn]);
                float cl = bflo(c2c[nn]), ch = bfhi(c2c[nn]);
                float gs0 = fmaf(w2v[0][0], gA0.c[nn], fmaf(w2v[1][0], gB0.c[nn], w2v[2][0] * gC0.c[nn]));
                float gs1 = fmaf(w2v[0][1], gA1.c[nn], fmaf(w2v[1][1], gB1.c[nn], w2v[2][1] * gC1.c[nn]));
                float P0 = __builtin_amdgcn_rcpf(1.f + __builtin_amdgcn_exp2f(fmaf(acn2x, cl, btn2x)));
                float P1 = __builtin_amdgcn_rcpf(1.f + __builtin_amdgcn_exp2f(fmaf(acn2y, ch, btn2y)));
                float d0 = a2.x - rl, d1 = a2.y - rh;
                acc.c[nn] = (gs0 + P0 * (d0 * d0 - gs0)) + (gs1 + P1 * (d1 * d1 - gs1));
            }
        }
        // L0 for g+1 -> v0[(g+1)&1]
        {
            F4 v0a, v0b;
#pragma unroll
            for (int nn = 0; nn < 4; ++nn) {
                float d0 = a0.x - bflo(r0n[nn]);
                float d1 = a0.y - bfhi(r0n[nn]);
                v0a.c[nn] = d0 * d0;
                v0b.c[nn] = d1 * d1;
            }
            qw0a[((g + 1) & 1) * 512] = v0a;
            qw0b[((g + 1) & 1) * 512] = v0b;
        }
        // wave reduction: 10-shuffle split butterfly
        {
            float pA = __shfl_xor(acc.c[0], 1);
            float pB = __shfl_xor(acc.c[1], 1);
            float pC = __shfl_xor(acc.c[2], 1);
            float pD = __shfl_xor(acc.c[3], 1);
            float u0, u1;
            if (lane & 1) { u0 = acc.c[1] + pB; u1 = acc.c[3] + pD; }
            else          { u0 = acc.c[0] + pA; u1 = acc.c[2] + pC; }
            float q0 = __shfl_xor(u0, 2);
            float q1 = __shfl_xor(u1, 2);
            float v = (lane & 2) ? (u1 + q1) : (u0 + q0);   // holds nn = lane&3
            v += __shfl_xor(v, 4);
            v += __shfl_xor(v, 8);
            v += __shfl_xor(v, 16);
            v += __shfl_xor(v, 32);
            if (lane < 4) pbuf[wid * 4 + lane] = v;
        }
        __syncthreads();

        // rotate prefetched data / advance pointers
#pragma unroll
        for (int nn = 0; nn < 4; ++nn) { r1c[nn] = r1n[nn]; c1c[nn] = c1n[nn]; }
        pr0 += 4 * D; pr1 += 4 * D; pr2 += 4 * D; pc1 += 4 * D; pc2 += 4 * D;
    }

    // epilogue: out-write for g=7
    if (tid < 4)
        out[(size_t)b * NB2 + n0 + 28 + tid] =
            pbuf[tid] + pbuf[4 + tid] + pbuf[8 + tid] + pbuf[12 + tid];
}

extern "C" void kernel_launch(void* const* d_in, const int* in_sizes, int n_in,
                              void* d_out, int out_size, void* d_ws, size_t ws_size,
                              hipStream_t stream) {
    const float* emb1  = (const float*)d_in[0];  // (3,256,512)
    const float* cert1 = (const float*)d_in[1];  // (3,256,512)
    const float* emb2  = (const float*)d_in[2];  // (3,512,512)
    const float* cert2 = (const float*)d_in[3];  // (3,512,512)
    const float* links = (const float*)d_in[4];  // (2,512,512)
    const float* alpha = (const float*)d_in[5];  // (2,512)
    const float* beta  = (const float*)d_in[6];  // (2,512)
    float* out = (float*)d_out;                  // (256,512)

    float* n1      = (float*)d_ws;                      // 3*256*512 f32
    ushort_t* n2h  = (ushort_t*)(n1 + 3 * NB1 * D);     // 3*512*512 bf16
    ushort_t* c2h  = n2h + 3 * NB2 * D;                 // 2*512*512 bf16
    uint_t* pidx   = (uint_t*)(c2h + 2 * NB2 * D);      // 2*512 u32
    float* wval    = (float*)(pidx + 2 * D);            // 2*3*512 f32

    hipLaunchKernelGGL(prep_kernel, dim3(1344), dim3(256), 0, stream,
                       emb1, emb2, cert2, links, n1, n2h, c2h, pidx, wval);
    hipLaunchKernelGGL(avsl_main_kernel, dim3(4096), dim3(256), 0, stream,
                       n1, n2h, cert1, c2h, pidx, wval, alpha, beta, out);
}